// Round 21
// baseline (53.388 us; speedup 1.0000x reference)
//
#include <hip/hip_runtime.h>
#include <hip/hip_fp16.h>

#define IN_DIM  16384
#define OUT_DIM 16384
#define BATCH   2048
#define TPB     512
#define NBLK    (BATCH / 4)             // 512 blocks, 4 rows each
#define ITS     (OUT_DIM / (TPB * 4))   // 8 j-iterations (4 columns each)
#define CHK     (IN_DIM / (TPB * 8))    // 4 stage chunks of 8 columns per thread

typedef float f32x4 __attribute__((ext_vector_type(4)));

// Two half2's per output column: ab = (c0, c1), cd = (c2, c3). 8 bytes.
struct h2x2 { __half2 ab, cd; };

// OP_COEFFS from the reference, row-major [16][4]
__device__ __constant__ float OPC[16][4] = {
    {0.f, 0.f, 0.f, 0.f}, {0.f, 0.f, 0.f, 1.f}, {0.f, 1.f, 0.f, -1.f}, {0.f, 1.f, 0.f, 0.f},
    {0.f, 0.f, 1.f, -1.f}, {0.f, 0.f, 1.f, 0.f}, {0.f, 1.f, 1.f, -2.f}, {0.f, 1.f, 1.f, -1.f},
    {1.f, -1.f, -1.f, 1.f}, {1.f, -1.f, -1.f, 2.f}, {1.f, 0.f, -1.f, 0.f}, {1.f, 0.f, -1.f, 1.f},
    {1.f, -1.f, 0.f, 0.f}, {1.f, -1.f, 0.f, 1.f}, {1.f, 0.f, 0.f, -1.f}, {1.f, 0.f, 0.f, 0.f}};

// Prep: coef (f16x4) + packed RAW indices: idx_a | idx_b<<16 (byte offset = idx*8).
__global__ __launch_bounds__(64) void prep_kernel(const float* __restrict__ w,
                                                  const int* __restrict__ ia,
                                                  const int* __restrict__ ib,
                                                  h2x2* __restrict__ coefh,
                                                  unsigned* __restrict__ packed) {
    int j = blockIdx.x * 64 + threadIdx.x;
    if (j >= OUT_DIM) return;

    const float4* wr = (const float4*)(w + (size_t)j * 16);
    float wv[16];
    float4 w0 = wr[0], w1 = wr[1], w2 = wr[2], w3 = wr[3];
    wv[0] = w0.x; wv[1] = w0.y; wv[2] = w0.z; wv[3] = w0.w;
    wv[4] = w1.x; wv[5] = w1.y; wv[6] = w1.z; wv[7] = w1.w;
    wv[8] = w2.x; wv[9] = w2.y; wv[10] = w2.z; wv[11] = w2.w;
    wv[12] = w3.x; wv[13] = w3.y; wv[14] = w3.z; wv[15] = w3.w;

    float m = wv[0];
#pragma unroll
    for (int k = 1; k < 16; ++k) m = fmaxf(m, wv[k]);
    float s = 0.f;
#pragma unroll
    for (int k = 0; k < 16; ++k) { wv[k] = expf(wv[k] - m); s += wv[k]; }
    float inv = 1.f / s;

    float c0 = 0.f, c1 = 0.f, c2 = 0.f, c3 = 0.f;
#pragma unroll
    for (int k = 0; k < 16; ++k) {
        float p = wv[k];
        c0 = fmaf(p, OPC[k][0], c0);
        c1 = fmaf(p, OPC[k][1], c1);
        c2 = fmaf(p, OPC[k][2], c2);
        c3 = fmaf(p, OPC[k][3], c3);
    }
    h2x2 c;
    c.ab = __floats2half2_rn(c0 * inv, c1 * inv);
    c.cd = __floats2half2_rn(c2 * inv, c3 * inv);
    coefh[j] = c;
    packed[j] = (unsigned)ia[j] | ((unsigned)ib[j] << 16);
}

__device__ __forceinline__ unsigned pack2(float a, float b) {
    return __builtin_bit_cast(unsigned, __builtin_amdgcn_cvt_pkrtz(a, b));
}

// Quad-row f16 single-shot: one block stages FOUR rows interleaved in LDS,
// column i at byte 8i = {r0,r1,r2,r3 as 4x f16}. One ds_read_b64 per operand
// serves 4 outputs -> wave LDS-read count and conflict cycles halve vs the
// 2-row pair (R7/R13/R19: halving measured at each doubling). 128 KiB LDS ->
// 1 block/CU, 512 blocks = 2 rounds. (512,1) -> 256-VGPR cap (decoder ring),
// demand ~110 -> no spill. NT out-stores + depth-1 pi/cf prefetch kept.
__global__ __launch_bounds__(TPB, 1) void logic_kernel(const float* __restrict__ x,
                                                       const unsigned* __restrict__ packed,
                                                       const h2x2* __restrict__ coefh,
                                                       float* __restrict__ out) {
    __shared__ __half lds[4 * IN_DIM];  // 128 KiB quad-row interleave

    const int tid = threadIdx.x;
    const size_t row0 = (size_t)blockIdx.x * 4;

    // Stage 4 rows, chunked (chunk batching was neutral in R20).
    {
        const float4* s0 = (const float4*)(x + (row0 + 0) * IN_DIM);
        const float4* s1 = (const float4*)(x + (row0 + 1) * IN_DIM);
        const float4* s2 = (const float4*)(x + (row0 + 2) * IN_DIM);
        const float4* s3 = (const float4*)(x + (row0 + 3) * IN_DIM);
#pragma unroll
        for (int c = 0; c < CHK; ++c) {
            const int m = (c * TPB + tid) * 2;  // float4 index (8 columns)
            float4 r0a = s0[m], r0b = s0[m + 1];
            float4 r1a = s1[m], r1b = s1[m + 1];
            float4 r2a = s2[m], r2b = s2[m + 1];
            float4 r3a = s3[m], r3b = s3[m + 1];
            uint4 t0, t1, t2, t3;
            t0.x = pack2(r0a.x, r1a.x); t0.y = pack2(r2a.x, r3a.x);
            t0.z = pack2(r0a.y, r1a.y); t0.w = pack2(r2a.y, r3a.y);
            t1.x = pack2(r0a.z, r1a.z); t1.y = pack2(r2a.z, r3a.z);
            t1.z = pack2(r0a.w, r1a.w); t1.w = pack2(r2a.w, r3a.w);
            t2.x = pack2(r0b.x, r1b.x); t2.y = pack2(r2b.x, r3b.x);
            t2.z = pack2(r0b.y, r1b.y); t2.w = pack2(r2b.y, r3b.y);
            t3.x = pack2(r0b.z, r1b.z); t3.y = pack2(r2b.z, r3b.z);
            t3.z = pack2(r0b.w, r1b.w); t3.w = pack2(r2b.w, r3b.w);
            char* dst = (char*)lds + (size_t)(c * TPB + tid) * 64;  // 8 cols x 8 B
            *(uint4*)(dst + 0)  = t0;
            *(uint4*)(dst + 16) = t1;
            *(uint4*)(dst + 32) = t2;
            *(uint4*)(dst + 48) = t3;
        }
    }

    // Prefetch iteration 0's pi/cf while waiting on the barrier.
    uint4 pi = *(const uint4*)(packed + tid * 4);
    h2x2 cA = coefh[tid * 4 + 0];
    h2x2 cB = coefh[tid * 4 + 1];
    h2x2 cC = coefh[tid * 4 + 2];
    h2x2 cD = coefh[tid * 4 + 3];

    __syncthreads();

    const char* bufc = (const char*)lds;
    float* outr0 = out + row0 * IN_DIM;
    float* outr1 = outr0 + IN_DIM;
    float* outr2 = outr1 + IN_DIM;
    float* outr3 = outr2 + IN_DIM;

#pragma unroll
    for (int it = 0; it < ITS; ++it) {
        // Next iteration's pi/cf fly under this iteration's gather+FMA+store.
        uint4 pin = pi;
        h2x2 nA = cA, nB = cB, nC = cC, nD = cD;
        if (it + 1 < ITS) {
            const int jn = ((it + 1) * TPB + tid) * 4;
            pin = *(const uint4*)(packed + jn);
            nA = coefh[jn + 0];
            nB = coefh[jn + 1];
            nC = coefh[jn + 2];
            nD = coefh[jn + 3];
        }
        __builtin_amdgcn_sched_barrier(0);  // keep prefetch issue ahead of compute

        const int j0 = (it * TPB + tid) * 4;
        f32x4 o0, o1, o2, o3;
#define COL(P, CF, FLD)                                                              \
        {                                                                            \
            uint2 qa = *(const uint2*)(bufc + (size_t)((P) & 0xFFFFu) * 8);          \
            uint2 qb = *(const uint2*)(bufc + (size_t)((P) >> 16) * 8);              \
            __half2 a01 = __builtin_bit_cast(__half2, qa.x);                         \
            __half2 a23 = __builtin_bit_cast(__half2, qa.y);                         \
            __half2 b01 = __builtin_bit_cast(__half2, qb.x);                         \
            __half2 b23 = __builtin_bit_cast(__half2, qb.y);                         \
            float c0 = __low2float(CF.ab), c1 = __high2float(CF.ab);                 \
            float c2 = __low2float(CF.cd), c3 = __high2float(CF.cd);                 \
            float a0 = __low2float(a01), a1 = __high2float(a01);                     \
            float a2 = __low2float(a23), a3 = __high2float(a23);                     \
            float b0 = __low2float(b01), b1 = __high2float(b01);                     \
            float b2 = __low2float(b23), b3 = __high2float(b23);                     \
            o0.FLD = fmaf(a0, fmaf(c3, b0, c1), fmaf(c2, b0, c0));                   \
            o1.FLD = fmaf(a1, fmaf(c3, b1, c1), fmaf(c2, b1, c0));                   \
            o2.FLD = fmaf(a2, fmaf(c3, b2, c1), fmaf(c2, b2, c0));                   \
            o3.FLD = fmaf(a3, fmaf(c3, b3, c1), fmaf(c2, b3, c0));                   \
        }
        COL(pi.x, cA, x)
        COL(pi.y, cB, y)
        COL(pi.z, cC, z)
        COL(pi.w, cD, w)
#undef COL
        __builtin_nontemporal_store(o0, (f32x4*)(outr0 + j0));
        __builtin_nontemporal_store(o1, (f32x4*)(outr1 + j0));
        __builtin_nontemporal_store(o2, (f32x4*)(outr2 + j0));
        __builtin_nontemporal_store(o3, (f32x4*)(outr3 + j0));

        pi = pin; cA = nA; cB = nB; cC = nC; cD = nD;
    }
}

extern "C" void kernel_launch(void* const* d_in, const int* in_sizes, int n_in,
                              void* d_out, int out_size, void* d_ws, size_t ws_size,
                              hipStream_t stream) {
    const float* x = (const float*)d_in[0];
    const int* ia = (const int*)d_in[1];
    const int* ib = (const int*)d_in[2];
    const float* w = (const float*)d_in[3];
    float* out = (float*)d_out;

    // ws layout: [0, 128 KiB) coefh h2x2[OUT_DIM]; [128 KiB, 192 KiB) packed u32[OUT_DIM]
    h2x2* coefh = (h2x2*)d_ws;
    unsigned* packed = (unsigned*)((char*)d_ws + (size_t)OUT_DIM * sizeof(h2x2));

    prep_kernel<<<OUT_DIM / 64, 64, 0, stream>>>(w, ia, ib, coefh, packed);
    logic_kernel<<<NBLK, TPB, 0, stream>>>(x, packed, coefh, out);
}

// Round 22
// 48.513 us; speedup vs baseline: 1.1005x; 1.1005x over previous
//
#include <hip/hip_runtime.h>
#include <hip/hip_fp16.h>

#define IN_DIM  16384
#define OUT_DIM 16384
#define BATCH   2048
#define TPB     512
#define NBLK    (BATCH / 2)             // 1024 blocks, 2 rows each
#define ITS     (OUT_DIM / (TPB * 4))   // 8 j-iterations (4 columns each)
#define CHK     (IN_DIM / (TPB * 8))    // 4 stage chunks of 8 columns per thread

typedef float f32x4 __attribute__((ext_vector_type(4)));

// Two half2's per output column: ab = (c0, c1), cd = (c2, c3). 8 bytes.
struct h2x2 { __half2 ab, cd; };

// OP_COEFFS from the reference, row-major [16][4]
__device__ __constant__ float OPC[16][4] = {
    {0.f, 0.f, 0.f, 0.f}, {0.f, 0.f, 0.f, 1.f}, {0.f, 1.f, 0.f, -1.f}, {0.f, 1.f, 0.f, 0.f},
    {0.f, 0.f, 1.f, -1.f}, {0.f, 0.f, 1.f, 0.f}, {0.f, 1.f, 1.f, -2.f}, {0.f, 1.f, 1.f, -1.f},
    {1.f, -1.f, -1.f, 1.f}, {1.f, -1.f, -1.f, 2.f}, {1.f, 0.f, -1.f, 0.f}, {1.f, 0.f, -1.f, 1.f},
    {1.f, -1.f, 0.f, 0.f}, {1.f, -1.f, 0.f, 1.f}, {1.f, 0.f, 0.f, -1.f}, {1.f, 0.f, 0.f, 0.f}};

// Prep: coef (f16x4) + packed pair-LDS byte offsets: (idx_a*4) | (idx_b*4)<<16.
__global__ __launch_bounds__(256) void prep_kernel(const float* __restrict__ w,
                                                   const int* __restrict__ ia,
                                                   const int* __restrict__ ib,
                                                   h2x2* __restrict__ coefh,
                                                   unsigned* __restrict__ packed) {
    int j = blockIdx.x * 256 + threadIdx.x;
    if (j >= OUT_DIM) return;

    const float4* wr = (const float4*)(w + (size_t)j * 16);
    float wv[16];
    float4 w0 = wr[0], w1 = wr[1], w2 = wr[2], w3 = wr[3];
    wv[0] = w0.x; wv[1] = w0.y; wv[2] = w0.z; wv[3] = w0.w;
    wv[4] = w1.x; wv[5] = w1.y; wv[6] = w1.z; wv[7] = w1.w;
    wv[8] = w2.x; wv[9] = w2.y; wv[10] = w2.z; wv[11] = w2.w;
    wv[12] = w3.x; wv[13] = w3.y; wv[14] = w3.z; wv[15] = w3.w;

    float m = wv[0];
#pragma unroll
    for (int k = 1; k < 16; ++k) m = fmaxf(m, wv[k]);
    float s = 0.f;
#pragma unroll
    for (int k = 0; k < 16; ++k) { wv[k] = expf(wv[k] - m); s += wv[k]; }
    float inv = 1.f / s;

    float c0 = 0.f, c1 = 0.f, c2 = 0.f, c3 = 0.f;
#pragma unroll
    for (int k = 0; k < 16; ++k) {
        float p = wv[k];
        c0 = fmaf(p, OPC[k][0], c0);
        c1 = fmaf(p, OPC[k][1], c1);
        c2 = fmaf(p, OPC[k][2], c2);
        c3 = fmaf(p, OPC[k][3], c3);
    }
    h2x2 c;
    c.ab = __floats2half2_rn(c0 * inv, c1 * inv);
    c.cd = __floats2half2_rn(c2 * inv, c3 * inv);
    coefh[j] = c;
    packed[j] = ((unsigned)ia[j] << 2) | ((unsigned)ib[j] << 18);
}

__device__ __forceinline__ unsigned pack2(float a, float b) {
    return __builtin_bit_cast(unsigned, __builtin_amdgcn_cvt_pkrtz(a, b));
}

// SESSION BEST (exact round-19 kernel, 48.66us): pair-row f16 single-shot +
// NT stores. 2 rows interleaved in LDS as half2{A[i],B[i]} at byte 4i
// (64 KiB, 2 blocks/CU). One ds_read_b32 serves BOTH rows per operand
// (conflicts 5.24M -> 3.16M measured). NT out-stores relieve the L2 write
// path (-5.4us measured). Depth-1 pi/cf prefetch hides L2 latency. The
// 4-row extension regressed (1 block/CU lost cross-block overlap, R21);
// batch-issued stage loads neutral (R20); quad/DMA/occupancy variants all
// neutral -> this is the plateau configuration.
__global__ __launch_bounds__(TPB, 2) void logic_kernel(const float* __restrict__ x,
                                                       const unsigned* __restrict__ packed,
                                                       const h2x2* __restrict__ coefh,
                                                       float* __restrict__ out) {
    __shared__ __half lds[2 * IN_DIM];  // 64 KiB interleaved pair buffer

    const int tid = threadIdx.x;
    const size_t rowA = (size_t)blockIdx.x * 2;

    // Stage both rows: 16 float4 loads, pack interleaved f16 pairs, 8x16B writes.
    {
        const float4* sA = (const float4*)(x + rowA * IN_DIM);
        const float4* sB = (const float4*)(x + (rowA + 1) * IN_DIM);
#pragma unroll
        for (int c = 0; c < CHK; ++c) {
            const int m = (c * TPB + tid) * 2;
            float4 a0 = sA[m + 0], a1 = sA[m + 1];
            float4 b0 = sB[m + 0], b1 = sB[m + 1];
            uint4 t0, t1;
            t0.x = pack2(a0.x, b0.x); t0.y = pack2(a0.y, b0.y);
            t0.z = pack2(a0.z, b0.z); t0.w = pack2(a0.w, b0.w);
            t1.x = pack2(a1.x, b1.x); t1.y = pack2(a1.y, b1.y);
            t1.z = pack2(a1.z, b1.z); t1.w = pack2(a1.w, b1.w);
            char* dst = (char*)lds + (size_t)(c * TPB + tid) * 32;
            *(uint4*)dst = t0;
            *(uint4*)(dst + 16) = t1;
        }
    }

    // Prefetch iteration 0's pi/cf while waiting on the barrier.
    uint4 pi = *(const uint4*)(packed + tid * 4);
    h2x2 cA = coefh[tid * 4 + 0];
    h2x2 cB = coefh[tid * 4 + 1];
    h2x2 cC = coefh[tid * 4 + 2];
    h2x2 cD = coefh[tid * 4 + 3];

    __syncthreads();

    const char* bufc = (const char*)lds;
    float* outrA = out + rowA * IN_DIM;
    float* outrB = outrA + IN_DIM;

#pragma unroll
    for (int it = 0; it < ITS; ++it) {
        // Next iteration's pi/cf fly under this iteration's gather+FMA+store.
        uint4 pin = pi;
        h2x2 nA = cA, nB = cB, nC = cC, nD = cD;
        if (it + 1 < ITS) {
            const int jn = ((it + 1) * TPB + tid) * 4;
            pin = *(const uint4*)(packed + jn);
            nA = coefh[jn + 0];
            nB = coefh[jn + 1];
            nC = coefh[jn + 2];
            nD = coefh[jn + 3];
        }
        __builtin_amdgcn_sched_barrier(0);  // keep prefetch issue ahead of compute

        const int j0 = (it * TPB + tid) * 4;
        f32x4 oA, oB;
#define COL(P, CF, FLD)                                                              \
        {                                                                            \
            __half2 ap = *(const __half2*)(bufc + ((P) & 0xFFFFu));                  \
            __half2 bp = *(const __half2*)(bufc + ((P) >> 16));                      \
            float aA = __low2float(ap), aB = __high2float(ap);                       \
            float bA = __low2float(bp), bB = __high2float(bp);                       \
            float c0 = __low2float(CF.ab), c1 = __high2float(CF.ab);                 \
            float c2 = __low2float(CF.cd), c3 = __high2float(CF.cd);                 \
            oA.FLD = fmaf(aA, fmaf(c3, bA, c1), fmaf(c2, bA, c0));                   \
            oB.FLD = fmaf(aB, fmaf(c3, bB, c1), fmaf(c2, bB, c0));                   \
        }
        COL(pi.x, cA, x)
        COL(pi.y, cB, y)
        COL(pi.z, cC, z)
        COL(pi.w, cD, w)
#undef COL
        __builtin_nontemporal_store(oA, (f32x4*)(outrA + j0));
        __builtin_nontemporal_store(oB, (f32x4*)(outrB + j0));

        pi = pin; cA = nA; cB = nB; cC = nC; cD = nD;
    }
}

extern "C" void kernel_launch(void* const* d_in, const int* in_sizes, int n_in,
                              void* d_out, int out_size, void* d_ws, size_t ws_size,
                              hipStream_t stream) {
    const float* x = (const float*)d_in[0];
    const int* ia = (const int*)d_in[1];
    const int* ib = (const int*)d_in[2];
    const float* w = (const float*)d_in[3];
    float* out = (float*)d_out;

    // ws layout: [0, 128 KiB) coefh h2x2[OUT_DIM]; [128 KiB, 192 KiB) packed u32[OUT_DIM]
    h2x2* coefh = (h2x2*)d_ws;
    unsigned* packed = (unsigned*)((char*)d_ws + (size_t)OUT_DIM * sizeof(h2x2));

    prep_kernel<<<OUT_DIM / 256, 256, 0, stream>>>(w, ia, ib, coefh, packed);
    logic_kernel<<<NBLK, TPB, 0, stream>>>(x, packed, coefh, out);
}